// Round 6
// baseline (475.817 us; speedup 1.0000x reference)
//
#include <hip/hip_runtime.h>

#define N 8192
#define D 512
#define KNEI 10
#define NC 8
#define GSPLIT 16
#define TRS 20
#define NTOT (GSPLIT * 2 * NC)  // 256 candidates per row

typedef __attribute__((ext_vector_type(8))) short bfv8;
typedef __attribute__((ext_vector_type(8))) unsigned short usv8;
typedef __attribute__((ext_vector_type(4))) float fv4;
typedef unsigned int uint32;

#define GLOAD_LDS16(gp, lp)                                                  \
  __builtin_amdgcn_global_load_lds(                                          \
      (const __attribute__((address_space(1))) void*)(gp),                   \
      (__attribute__((address_space(3))) void*)(lp), 16, 0, 0)

__device__ inline unsigned short f2bf(float f) {
  unsigned int u = __float_as_uint(f);
  return (unsigned short)((u + 0x7fffu + ((u >> 16) & 1u)) >> 16);
}

// ---------------------------------------------------------------------------
// Kernel 0: per-row fp32 sq (numpy-pairwise-style; validated rounds 3-5).
// ---------------------------------------------------------------------------
__global__ __launch_bounds__(256) void row_sq_np_kernel(const float* __restrict__ x,
                                                        float* __restrict__ sq) {
  const int wave = threadIdx.x >> 6;
  const int lane = threadIdx.x & 63;
  const int row = blockIdx.x * 4 + wave;
  const float* xr = x + (size_t)row * D;

  float s = 0.f;
  if (lane < 32) {
    const int leaf = lane >> 3;
    const int j = lane & 7;
    const float* a = xr + leaf * 128;
    float v = a[j];
    s = __fmul_rn(v, v);
#pragma unroll
    for (int i = 8; i < 128; i += 8) {
      v = a[i + j];
      s = __fadd_rn(s, __fmul_rn(v, v));
    }
  }
  float t1 = __shfl_xor(s, 1);
  s = __fadd_rn(s, t1);
  float t2 = __shfl_xor(s, 2);
  s = __fadd_rn(s, t2);
  float t4 = __shfl_xor(s, 4);
  s = __fadd_rn(s, t4);
  const float L0 = __shfl(s, 0);
  const float L1 = __shfl(s, 8);
  const float L2 = __shfl(s, 16);
  const float L3 = __shfl(s, 24);
  const float total = __fadd_rn(__fadd_rn(L0, L1), __fadd_rn(L2, L3));
  if (lane == 0) sq[row] = total;
}

// ---------------------------------------------------------------------------
// Kernel 0b: fp32 -> bf16 (RTNE).
// ---------------------------------------------------------------------------
__global__ __launch_bounds__(256) void cvt_bf16_kernel(const float* __restrict__ x,
                                                       unsigned short* __restrict__ xb) {
  const int base = (blockIdx.x * 256 + threadIdx.x) * 8;
  const float4 a = *(const float4*)(x + base);
  const float4 b = *(const float4*)(x + base + 4);
  usv8 o;
  o[0] = f2bf(a.x); o[1] = f2bf(a.y); o[2] = f2bf(a.z); o[3] = f2bf(a.w);
  o[4] = f2bf(b.x); o[5] = f2bf(b.y); o[6] = f2bf(b.z); o[7] = f2bf(b.w);
  *(usv8*)(xb + base) = o;
}

// ---------------------------------------------------------------------------
// Kernel 1: MFMA bf16 Gram + fused selection, 128x128 block tile.
// Grid (64,16). 4 waves in 2x2: wave (wy,wx) owns rows wy*64.., cols wx*64..
// Per kt (BK=64): stage A/B 128x64 via global_load_lds w16 (XOR-swizzled),
// 32 MFMA vs 16 ds_read_b128 per wave. Transpose+select in two 64-col phases.
// ---------------------------------------------------------------------------
__global__ __launch_bounds__(256, 3) void knn_gemm_mfma(
    const unsigned short* __restrict__ xb, const float* __restrict__ sq,
    uint32* __restrict__ ck) {
  __shared__ __align__(16) float Ct[64 * 136];  // 34816 B; staging aliased below
  __shared__ float sqj_s[128];
  unsigned short* As = (unsigned short*)Ct;             // 128x64 bf16 = 16 KB
  unsigned short* Bs = (unsigned short*)Ct + 128 * 64;  // 128x64 bf16 = 16 KB

  const int tid = threadIdx.x;
  const int lane = tid & 63;
  const int wave = tid >> 6;
  const int wy = wave >> 1;
  const int wx = wave & 1;
  const int m = lane & 15;
  const int kg = lane >> 4;
  const int ibase = blockIdx.x * 128;
  const int jstart = blockIdx.y * (N / GSPLIT);

  const int srow = lane >> 3;
  const int schunk = lane & 7;
  const int sko = (schunk ^ srow) * 8;  // XOR-swizzled source chunk

  uint32 bk[NC];
#pragma unroll
  for (int t = 0; t < NC; ++t) bk[t] = 0xffffffffu;

  const int selrow = tid & 127;
  const int selhalf = tid >> 7;
  const float sqi_own = sq[ibase + selrow];

  for (int jt = 0; jt < 4; ++jt) {
    const int jbase = jstart + jt * 128;

    fv4 acc[4][4];
#pragma unroll
    for (int fi = 0; fi < 4; ++fi)
#pragma unroll
      for (int fj = 0; fj < 4; ++fj) acc[fi][fj] = (fv4)(0.f);

    for (int kt = 0; kt < 8; ++kt) {
      const int k0 = kt * 64;
      __syncthreads();  // prior frag/Ct/sqj reads done; LDS reusable
      if (kt == 0 && tid < 128) sqj_s[tid] = sq[jbase + tid];
#pragma unroll
      for (int q = 0; q < 4; ++q) {
        const int rbase = wave * 8 + q * 32;
        GLOAD_LDS16(xb + (size_t)(ibase + rbase + srow) * D + k0 + sko,
                    As + rbase * 64);
      }
#pragma unroll
      for (int q = 0; q < 4; ++q) {
        const int rbase = wave * 8 + q * 32;
        GLOAD_LDS16(xb + (size_t)(jbase + rbase + srow) * D + k0 + sko,
                    Bs + rbase * 64);
      }
      __syncthreads();  // staging visible

#pragma unroll
      for (int kh = 0; kh < 2; ++kh) {
        bfv8 af[4], bf[4];
#pragma unroll
        for (int fi = 0; fi < 4; ++fi) {
          const int row = wy * 64 + fi * 16 + m;
          const int ch = (kh * 4 + kg) ^ (row & 7);
          af[fi] = *(const bfv8*)(As + row * 64 + ch * 8);
        }
#pragma unroll
        for (int fj = 0; fj < 4; ++fj) {
          const int row = wx * 64 + fj * 16 + m;
          const int ch = (kh * 4 + kg) ^ (row & 7);
          bf[fj] = *(const bfv8*)(Bs + row * 64 + ch * 8);
        }
#pragma unroll
        for (int fi = 0; fi < 4; ++fi)
#pragma unroll
          for (int fj = 0; fj < 4; ++fj)
            acc[fi][fj] = __builtin_amdgcn_mfma_f32_16x16x32_bf16(
                af[fi], bf[fj], acc[fi][fj], 0, 0, 0);
      }
    }

    // Two transpose+select phases (64 cols each).
#pragma unroll 1
    for (int ph = 0; ph < 2; ++ph) {
      __syncthreads();  // prior frag reads / prior-phase Ct reads done
      if (wx == ph) {
#pragma unroll
        for (int fi = 0; fi < 4; ++fi)
#pragma unroll
          for (int fj = 0; fj < 4; ++fj)
            *(fv4*)(&Ct[(fj * 16 + m) * 136 + wy * 64 + fi * 16 + kg * 4]) =
                acc[fi][fj];
      }
      __syncthreads();

      const int cb = selhalf * 32;
#pragma unroll 1
      for (int cc = 0; cc < 32; ++cc) {
        const int c = cb + cc;
        const float d =
            fmaxf(sqi_own - 2.f * Ct[c * 136 + selrow] + sqj_s[ph * 64 + c],
                  0.f);
        const uint32 key =
            ((uint32)f2bf(d) << 16) | (uint32)(jbase + ph * 64 + c);
        if (key < bk[NC - 1]) {
          uint32 kv = key;
#pragma unroll
          for (int t = 0; t < NC; ++t) {
            if (kv < bk[t]) {
              const uint32 tmp = bk[t];
              bk[t] = kv;
              kv = tmp;
            }
          }
        }
      }
    }
  }

  const size_t obase =
      ((size_t)(ibase + selrow) * GSPLIT + blockIdx.y) * 2 * NC +
      (size_t)selhalf * NC;
#pragma unroll
  for (int t = 0; t < NC; ++t) ck[obase + t] = bk[t];
}

// ---------------------------------------------------------------------------
// Kernel 2: per-row merge. Preselect top-20 of 256 packed keys; fp64 rescore
// (validated rounds 3-5) WITH LDS staging of the 20 candidate rows; serial
// top-10 eps tie-break; smoothing reads winners from LDS (no second gather).
// ---------------------------------------------------------------------------
__global__ __launch_bounds__(256) void merge_kernel(const float* __restrict__ x,
                                                    const float* __restrict__ sq,
                                                    const uint32* __restrict__ ck,
                                                    float* __restrict__ out) {
  __shared__ __align__(16) float xi[D];
  __shared__ __align__(16) float xc[TRS * D];  // 40 KB candidate rows
  __shared__ uint32 keys[NTOT];
  __shared__ int selc[TRS];
  __shared__ double zsh[TRS];
  __shared__ int sel[KNEI];  // winning candidate SLOTS (into xc/selc)

  const int i = blockIdx.x;
  const int tid = threadIdx.x;

  if (tid < 128) *(float4*)(&xi[tid * 4]) = *(const float4*)(x + (size_t)i * D + tid * 4);
  if (tid < NTOT) keys[tid] = ck[(size_t)i * NTOT + tid];
  __syncthreads();

  // (1) top-20 by packed key (bf16 score, then lower index — keys unique)
  if (tid < 64) {
    uint32 l0 = keys[tid], l1 = keys[tid + 64], l2 = keys[tid + 128],
           l3 = keys[tid + 192];
    for (int slot = 0; slot < TRS; ++slot) {
      uint32 r = min(min(l0, l1), min(l2, l3));
#pragma unroll
      for (int off = 32; off; off >>= 1) r = min(r, __shfl_xor(r, off));
      if (tid == 0) selc[slot] = (int)(r & 0xffffu);
      if (l0 == r) l0 = 0xffffffffu;
      if (l1 == r) l1 = 0xffffffffu;
      if (l2 == r) l2 = 0xffffffffu;
      if (l3 == r) l3 = 0xffffffffu;
    }
  }
  __syncthreads();

  const float sqi = sq[i];

  // (2) fp64 rescore, 8 threads/candidate; stage candidate rows into LDS.
  if (tid < 8 * TRS) {
    const int c = tid >> 3;
    const int p = tid & 7;
    const int j = selc[c];
    const float4* xj4 = (const float4*)(x + (size_t)j * D);
    const float4* xi4 = (const float4*)xi;
    double s = 0.0;
    for (int q = p * 16; q < p * 16 + 16; ++q) {
      const float4 a = xi4[q];
      const float4 b = xj4[q];
      *(float4*)(&xc[c * D + q * 4]) = b;
      s += (double)a.x * (double)b.x + (double)a.y * (double)b.y +
           (double)a.z * (double)b.z + (double)a.w * (double)b.w;
    }
    s += __shfl_xor(s, 1);
    s += __shfl_xor(s, 2);
    s += __shfl_xor(s, 4);
    if (p == 0) {
      const float G = (float)s;
      const float y = __fsub_rn(sqi, __fmul_rn(2.0f, G));
      zsh[c] = (double)y + (double)sq[j];
    }
  }
  __syncthreads();

  // (3) serial top-10, eps tie-break (lower index within 1.25e-7 rel) —
  // comparator byte-identical to the validated round-3/4/5 version.
  if (tid == 0) {
    unsigned int used = 0u;
    for (int slot = 0; slot < KNEI; ++slot) {
      int b = -1;
      double zb = 0.0;
      for (int c = 0; c < TRS; ++c) {
        if ((used >> c) & 1u) continue;
        const double zc = zsh[c];
        if (b < 0) {
          b = c;
          zb = zc;
          continue;
        }
        const double eps = 1.25e-7 * fabs(zb);
        bool better;
        if (zc < zb - eps) better = true;
        else if (zc > zb + eps) better = false;
        else better = (selc[c] < selc[b]);
        if (better) {
          b = c;
          zb = zc;
        }
      }
      used |= (1u << b);
      sel[slot] = b;  // slot index — smoothing reads xc[b]
    }
  }
  __syncthreads();

  // (4) smoothed = 0.5*x + 0.05 * sum(neighbors) — all from LDS.
  for (int k = tid; k < D; k += 256) {
    float a = 0.f;
#pragma unroll
    for (int mth = 0; mth < KNEI; ++mth) a += xc[sel[mth] * D + k];
    out[(size_t)i * D + k] = 0.5f * xi[k] + 0.05f * a;
  }
}

// ---------------------------------------------------------------------------
extern "C" void kernel_launch(void* const* d_in, const int* in_sizes, int n_in,
                              void* d_out, int out_size, void* d_ws, size_t ws_size,
                              hipStream_t stream) {
  const float* x = (const float*)d_in[0];
  float* out = (float*)d_out;

  char* ws = (char*)d_ws;
  float* sq = (float*)ws;                              // 32 KB
  unsigned short* xb = (unsigned short*)(ws + 32768);  // 8 MB
  uint32* ck = (uint32*)(ws + 32768 + 8388608);        // 8 MB

  row_sq_np_kernel<<<N / 4, 256, 0, stream>>>(x, sq);
  cvt_bf16_kernel<<<(N * D) / (8 * 256), 256, 0, stream>>>(x, xb);
  knn_gemm_mfma<<<dim3(N / 128, GSPLIT), 256, 0, stream>>>(xb, sq, ck);
  merge_kernel<<<N, 256, 0, stream>>>(x, sq, ck, out);
}

// Round 7
// 362.633 us; speedup vs baseline: 1.3121x; 1.3121x over previous
//
#include <hip/hip_runtime.h>

#define N 8192
#define D 512
#define KNEI 10
#define NC 8
#define GSPLIT 16
#define TRS 20
#define NTOT (GSPLIT * 2 * NC)  // 256 candidates per row

typedef __attribute__((ext_vector_type(8))) short bfv8;
typedef __attribute__((ext_vector_type(8))) unsigned short usv8;
typedef __attribute__((ext_vector_type(4))) float fv4;
typedef unsigned int uint32;

#define GLOAD_LDS16(gp, lp)                                                  \
  __builtin_amdgcn_global_load_lds(                                          \
      (const __attribute__((address_space(1))) void*)(gp),                   \
      (__attribute__((address_space(3))) void*)(lp), 16, 0, 0)

__device__ inline unsigned short f2bf(float f) {
  unsigned int u = __float_as_uint(f);
  return (unsigned short)((u + 0x7fffu + ((u >> 16) & 1u)) >> 16);
}

// ---------------------------------------------------------------------------
// Kernel 0: per-row fp32 sq (numpy-pairwise-style; validated rounds 3-6).
// ---------------------------------------------------------------------------
__global__ __launch_bounds__(256) void row_sq_np_kernel(const float* __restrict__ x,
                                                        float* __restrict__ sq) {
  const int wave = threadIdx.x >> 6;
  const int lane = threadIdx.x & 63;
  const int row = blockIdx.x * 4 + wave;
  const float* xr = x + (size_t)row * D;

  float s = 0.f;
  if (lane < 32) {
    const int leaf = lane >> 3;
    const int j = lane & 7;
    const float* a = xr + leaf * 128;
    float v = a[j];
    s = __fmul_rn(v, v);
#pragma unroll
    for (int i = 8; i < 128; i += 8) {
      v = a[i + j];
      s = __fadd_rn(s, __fmul_rn(v, v));
    }
  }
  float t1 = __shfl_xor(s, 1);
  s = __fadd_rn(s, t1);
  float t2 = __shfl_xor(s, 2);
  s = __fadd_rn(s, t2);
  float t4 = __shfl_xor(s, 4);
  s = __fadd_rn(s, t4);
  const float L0 = __shfl(s, 0);
  const float L1 = __shfl(s, 8);
  const float L2 = __shfl(s, 16);
  const float L3 = __shfl(s, 24);
  const float total = __fadd_rn(__fadd_rn(L0, L1), __fadd_rn(L2, L3));
  if (lane == 0) sq[row] = total;
}

// ---------------------------------------------------------------------------
// Kernel 0b: fp32 -> bf16 (RTNE).
// ---------------------------------------------------------------------------
__global__ __launch_bounds__(256) void cvt_bf16_kernel(const float* __restrict__ x,
                                                       unsigned short* __restrict__ xb) {
  const int base = (blockIdx.x * 256 + threadIdx.x) * 8;
  const float4 a = *(const float4*)(x + base);
  const float4 b = *(const float4*)(x + base + 4);
  usv8 o;
  o[0] = f2bf(a.x); o[1] = f2bf(a.y); o[2] = f2bf(a.z); o[3] = f2bf(a.w);
  o[4] = f2bf(b.x); o[5] = f2bf(b.y); o[6] = f2bf(b.z); o[7] = f2bf(b.w);
  *(usv8*)(xb + base) = o;
}

// ---------------------------------------------------------------------------
// Kernel 1: MFMA bf16 Gram + fused selection, 128x128 block tile (round-6,
// kept UNCHANGED this round so its true duration shows in the profile).
// ---------------------------------------------------------------------------
__global__ __launch_bounds__(256, 3) void knn_gemm_mfma(
    const unsigned short* __restrict__ xb, const float* __restrict__ sq,
    uint32* __restrict__ ck) {
  __shared__ __align__(16) float Ct[64 * 136];  // 34816 B; staging aliased below
  __shared__ float sqj_s[128];
  unsigned short* As = (unsigned short*)Ct;             // 128x64 bf16 = 16 KB
  unsigned short* Bs = (unsigned short*)Ct + 128 * 64;  // 128x64 bf16 = 16 KB

  const int tid = threadIdx.x;
  const int lane = tid & 63;
  const int wave = tid >> 6;
  const int wy = wave >> 1;
  const int wx = wave & 1;
  const int m = lane & 15;
  const int kg = lane >> 4;
  const int ibase = blockIdx.x * 128;
  const int jstart = blockIdx.y * (N / GSPLIT);

  const int srow = lane >> 3;
  const int schunk = lane & 7;
  const int sko = (schunk ^ srow) * 8;  // XOR-swizzled source chunk

  uint32 bk[NC];
#pragma unroll
  for (int t = 0; t < NC; ++t) bk[t] = 0xffffffffu;

  const int selrow = tid & 127;
  const int selhalf = tid >> 7;
  const float sqi_own = sq[ibase + selrow];

  for (int jt = 0; jt < 4; ++jt) {
    const int jbase = jstart + jt * 128;

    fv4 acc[4][4];
#pragma unroll
    for (int fi = 0; fi < 4; ++fi)
#pragma unroll
      for (int fj = 0; fj < 4; ++fj) acc[fi][fj] = (fv4)(0.f);

    for (int kt = 0; kt < 8; ++kt) {
      const int k0 = kt * 64;
      __syncthreads();  // prior frag/Ct/sqj reads done; LDS reusable
      if (kt == 0 && tid < 128) sqj_s[tid] = sq[jbase + tid];
#pragma unroll
      for (int q = 0; q < 4; ++q) {
        const int rbase = wave * 8 + q * 32;
        GLOAD_LDS16(xb + (size_t)(ibase + rbase + srow) * D + k0 + sko,
                    As + rbase * 64);
      }
#pragma unroll
      for (int q = 0; q < 4; ++q) {
        const int rbase = wave * 8 + q * 32;
        GLOAD_LDS16(xb + (size_t)(jbase + rbase + srow) * D + k0 + sko,
                    Bs + rbase * 64);
      }
      __syncthreads();  // staging visible

#pragma unroll
      for (int kh = 0; kh < 2; ++kh) {
        bfv8 af[4], bf[4];
#pragma unroll
        for (int fi = 0; fi < 4; ++fi) {
          const int row = wy * 64 + fi * 16 + m;
          const int ch = (kh * 4 + kg) ^ (row & 7);
          af[fi] = *(const bfv8*)(As + row * 64 + ch * 8);
        }
#pragma unroll
        for (int fj = 0; fj < 4; ++fj) {
          const int row = wx * 64 + fj * 16 + m;
          const int ch = (kh * 4 + kg) ^ (row & 7);
          bf[fj] = *(const bfv8*)(Bs + row * 64 + ch * 8);
        }
#pragma unroll
        for (int fi = 0; fi < 4; ++fi)
#pragma unroll
          for (int fj = 0; fj < 4; ++fj)
            acc[fi][fj] = __builtin_amdgcn_mfma_f32_16x16x32_bf16(
                af[fi], bf[fj], acc[fi][fj], 0, 0, 0);
      }
    }

    // Two transpose+select phases (64 cols each).
#pragma unroll 1
    for (int ph = 0; ph < 2; ++ph) {
      __syncthreads();  // prior frag reads / prior-phase Ct reads done
      if (wx == ph) {
#pragma unroll
        for (int fi = 0; fi < 4; ++fi)
#pragma unroll
          for (int fj = 0; fj < 4; ++fj)
            *(fv4*)(&Ct[(fj * 16 + m) * 136 + wy * 64 + fi * 16 + kg * 4]) =
                acc[fi][fj];
      }
      __syncthreads();

      const int cb = selhalf * 32;
#pragma unroll 1
      for (int cc = 0; cc < 32; ++cc) {
        const int c = cb + cc;
        const float d =
            fmaxf(sqi_own - 2.f * Ct[c * 136 + selrow] + sqj_s[ph * 64 + c],
                  0.f);
        const uint32 key =
            ((uint32)f2bf(d) << 16) | (uint32)(jbase + ph * 64 + c);
        if (key < bk[NC - 1]) {
          uint32 kv = key;
#pragma unroll
          for (int t = 0; t < NC; ++t) {
            if (kv < bk[t]) {
              const uint32 tmp = bk[t];
              bk[t] = kv;
              kv = tmp;
            }
          }
        }
      }
    }
  }

  const size_t obase =
      ((size_t)(ibase + selrow) * GSPLIT + blockIdx.y) * 2 * NC +
      (size_t)selhalf * NC;
#pragma unroll
  for (int t = 0; t < NC; ++t) ck[obase + t] = bk[t];
}

// ---------------------------------------------------------------------------
// Kernel 2: per-row merge — ROUND-5 STRUCTURE RESTORED (validated ~130 µs):
// no xc LDS staging (it caused 2.75e7 bank conflicts + 33% occupancy cap).
// Preselect top-20 of 256 packed keys; fp64 rescore with the reference's
// fp32 rounding chain; serial top-10 eps tie-break; smoothing gathers winner
// rows from global (L2/L3-resident).
// ---------------------------------------------------------------------------
__global__ __launch_bounds__(256) void merge_kernel(const float* __restrict__ x,
                                                    const float* __restrict__ sq,
                                                    const uint32* __restrict__ ck,
                                                    float* __restrict__ out) {
  __shared__ __align__(16) float xi[D];
  __shared__ uint32 keys[NTOT];
  __shared__ int selc[TRS];
  __shared__ double zsh[TRS];
  __shared__ int sel[KNEI];

  const int i = blockIdx.x;
  const int tid = threadIdx.x;

  if (tid < 128)
    *(float4*)(&xi[tid * 4]) = *(const float4*)(x + (size_t)i * D + tid * 4);
  if (tid < NTOT) keys[tid] = ck[(size_t)i * NTOT + tid];
  __syncthreads();

  // (1) top-20 by packed key (bf16 score, then lower index — keys unique)
  if (tid < 64) {
    uint32 l0 = keys[tid], l1 = keys[tid + 64], l2 = keys[tid + 128],
           l3 = keys[tid + 192];
    for (int slot = 0; slot < TRS; ++slot) {
      uint32 r = min(min(l0, l1), min(l2, l3));
#pragma unroll
      for (int off = 32; off; off >>= 1) r = min(r, __shfl_xor(r, off));
      if (tid == 0) selc[slot] = (int)(r & 0xffffu);
      if (l0 == r) l0 = 0xffffffffu;
      if (l1 == r) l1 = 0xffffffffu;
      if (l2 == r) l2 = 0xffffffffu;
      if (l3 == r) l3 = 0xffffffffu;
    }
  }
  __syncthreads();

  const float sqi = sq[i];

  // (2) fp64 rescore, 8 threads per candidate.
  if (tid < 8 * TRS) {
    const int c = tid >> 3;
    const int p = tid & 7;
    const int j = selc[c];
    const float4* xj4 = (const float4*)(x + (size_t)j * D);
    const float4* xi4 = (const float4*)xi;
    double s = 0.0;
    for (int q = p * 16; q < p * 16 + 16; ++q) {
      const float4 a = xi4[q];
      const float4 b = xj4[q];
      s += (double)a.x * (double)b.x + (double)a.y * (double)b.y +
           (double)a.z * (double)b.z + (double)a.w * (double)b.w;
    }
    s += __shfl_xor(s, 1);
    s += __shfl_xor(s, 2);
    s += __shfl_xor(s, 4);
    if (p == 0) {
      const float G = (float)s;
      const float y = __fsub_rn(sqi, __fmul_rn(2.0f, G));
      zsh[c] = (double)y + (double)sq[j];
    }
  }
  __syncthreads();

  // (3) serial top-10, eps tie-break (lower index within 1.25e-7 rel) —
  // comparator byte-identical to the validated round-3/4/5 version.
  if (tid == 0) {
    unsigned int used = 0u;
    for (int slot = 0; slot < KNEI; ++slot) {
      int b = -1;
      double zb = 0.0;
      for (int c = 0; c < TRS; ++c) {
        if ((used >> c) & 1u) continue;
        const double zc = zsh[c];
        if (b < 0) {
          b = c;
          zb = zc;
          continue;
        }
        const double eps = 1.25e-7 * fabs(zb);
        bool better;
        if (zc < zb - eps) better = true;
        else if (zc > zb + eps) better = false;
        else better = (selc[c] < selc[b]);
        if (better) {
          b = c;
          zb = zc;
        }
      }
      used |= (1u << b);
      sel[slot] = selc[b];
    }
  }
  __syncthreads();

  // (4) smoothed = 0.5*x + 0.05 * sum(neighbors)
  for (int k = tid; k < D; k += 256) {
    float a = 0.f;
#pragma unroll
    for (int mth = 0; mth < KNEI; ++mth) a += x[(size_t)sel[mth] * D + k];
    out[(size_t)i * D + k] = 0.5f * xi[k] + 0.05f * a;
  }
}

// ---------------------------------------------------------------------------
extern "C" void kernel_launch(void* const* d_in, const int* in_sizes, int n_in,
                              void* d_out, int out_size, void* d_ws, size_t ws_size,
                              hipStream_t stream) {
  const float* x = (const float*)d_in[0];
  float* out = (float*)d_out;

  char* ws = (char*)d_ws;
  float* sq = (float*)ws;                              // 32 KB
  unsigned short* xb = (unsigned short*)(ws + 32768);  // 8 MB
  uint32* ck = (uint32*)(ws + 32768 + 8388608);        // 8 MB

  row_sq_np_kernel<<<N / 4, 256, 0, stream>>>(x, sq);
  cvt_bf16_kernel<<<(N * D) / (8 * 256), 256, 0, stream>>>(x, xb);
  knn_gemm_mfma<<<dim3(N / 128, GSPLIT), 256, 0, stream>>>(xb, sq, ck);
  merge_kernel<<<N, 256, 0, stream>>>(x, sq, ck, out);
}

// Round 8
// 267.120 us; speedup vs baseline: 1.7813x; 1.3576x over previous
//
#include <hip/hip_runtime.h>

#define N 8192
#define D 512
#define KNEI 10
#define NC 8
#define GSPLIT 16
#define TRS 20
#define NTOT (GSPLIT * 2 * NC)  // 256 candidates per row

typedef __attribute__((ext_vector_type(8))) short bfv8;
typedef __attribute__((ext_vector_type(8))) unsigned short usv8;
typedef __attribute__((ext_vector_type(4))) float fv4;
typedef unsigned int uint32;

#define GLOAD_LDS16(gp, lp)                                                  \
  __builtin_amdgcn_global_load_lds(                                          \
      (const __attribute__((address_space(1))) void*)(gp),                   \
      (__attribute__((address_space(3))) void*)(lp), 16, 0, 0)

__device__ inline unsigned short f2bf(float f) {
  unsigned int u = __float_as_uint(f);
  return (unsigned short)((u + 0x7fffu + ((u >> 16) & 1u)) >> 16);
}

// ---------------------------------------------------------------------------
// Kernel 0: per-row fp32 sq (numpy-pairwise-style; validated rounds 3-7).
// ---------------------------------------------------------------------------
__global__ __launch_bounds__(256) void row_sq_np_kernel(const float* __restrict__ x,
                                                        float* __restrict__ sq) {
  const int wave = threadIdx.x >> 6;
  const int lane = threadIdx.x & 63;
  const int row = blockIdx.x * 4 + wave;
  const float* xr = x + (size_t)row * D;

  float s = 0.f;
  if (lane < 32) {
    const int leaf = lane >> 3;
    const int j = lane & 7;
    const float* a = xr + leaf * 128;
    float v = a[j];
    s = __fmul_rn(v, v);
#pragma unroll
    for (int i = 8; i < 128; i += 8) {
      v = a[i + j];
      s = __fadd_rn(s, __fmul_rn(v, v));
    }
  }
  float t1 = __shfl_xor(s, 1);
  s = __fadd_rn(s, t1);
  float t2 = __shfl_xor(s, 2);
  s = __fadd_rn(s, t2);
  float t4 = __shfl_xor(s, 4);
  s = __fadd_rn(s, t4);
  const float L0 = __shfl(s, 0);
  const float L1 = __shfl(s, 8);
  const float L2 = __shfl(s, 16);
  const float L3 = __shfl(s, 24);
  const float total = __fadd_rn(__fadd_rn(L0, L1), __fadd_rn(L2, L3));
  if (lane == 0) sq[row] = total;
}

// ---------------------------------------------------------------------------
// Kernel 0b: fp32 -> bf16 (RTNE).
// ---------------------------------------------------------------------------
__global__ __launch_bounds__(256) void cvt_bf16_kernel(const float* __restrict__ x,
                                                       unsigned short* __restrict__ xb) {
  const int base = (blockIdx.x * 256 + threadIdx.x) * 8;
  const float4 a = *(const float4*)(x + base);
  const float4 b = *(const float4*)(x + base + 4);
  usv8 o;
  o[0] = f2bf(a.x); o[1] = f2bf(a.y); o[2] = f2bf(a.z); o[3] = f2bf(a.w);
  o[4] = f2bf(b.x); o[5] = f2bf(b.y); o[6] = f2bf(b.z); o[7] = f2bf(b.w);
  *(usv8*)(xb + base) = o;
}

// ---------------------------------------------------------------------------
// Kernel 1: MFMA bf16 Gram + fused selection — ROUND-5 VERSION RESTORED
// (validated 142 µs; the 128x128 variant regressed to 183 µs on occupancy).
// 32x64 wave tile, GSPLIT 16, global_load_lds w16, XOR-swizzled chunks.
// ---------------------------------------------------------------------------
__global__ __launch_bounds__(256, 4) void knn_gemm_mfma(
    const unsigned short* __restrict__ xb, const float* __restrict__ sq,
    uint32* __restrict__ ck) {
  __shared__ __align__(16) float Ct[64 * 136];  // 34816 B
  __shared__ float sqj_s[64];
  unsigned short* As = (unsigned short*)Ct;            // 128x64 bf16 = 16384 B
  unsigned short* Bs = (unsigned short*)Ct + 128 * 64; // 64x64 bf16 =  8192 B

  const int tid = threadIdx.x;
  const int lane = tid & 63;
  const int wave = tid >> 6;
  const int m = lane & 15;
  const int kg = lane >> 4;
  const int ibase = blockIdx.x * 128;
  const int jstart = blockIdx.y * (N / GSPLIT);

  const int srow = lane >> 3;
  const int schunk = lane & 7;
  const int sko = (schunk ^ srow) * 8;  // XOR-swizzled source k-offset

  uint32 bk[NC];
#pragma unroll
  for (int t = 0; t < NC; ++t) bk[t] = 0xffffffffu;

  const int selrow = tid & 127;
  const int selhalf = tid >> 7;
  const float sqi_own = sq[ibase + selrow];

  for (int jt = 0; jt < 8; ++jt) {
    const int jbase = jstart + jt * 64;

    fv4 acc[2][4];
#pragma unroll
    for (int fi = 0; fi < 2; ++fi)
#pragma unroll
      for (int fj = 0; fj < 4; ++fj) acc[fi][fj] = (fv4)(0.f);

    for (int kt = 0; kt < 8; ++kt) {
      const int k0 = kt * 64;
      __syncthreads();  // prior frag/Ct/sqj reads done; LDS reusable
      if (kt == 0 && tid < 64) sqj_s[tid] = sq[jbase + tid];
#pragma unroll
      for (int q = 0; q < 4; ++q) {
        const int rbase = wave * 8 + q * 32;
        GLOAD_LDS16(xb + (size_t)(ibase + rbase + srow) * D + k0 + sko,
                    As + rbase * 64);
      }
#pragma unroll
      for (int q = 0; q < 2; ++q) {
        const int rbase = wave * 8 + q * 32;
        GLOAD_LDS16(xb + (size_t)(jbase + rbase + srow) * D + k0 + sko,
                    Bs + rbase * 64);
      }
      __syncthreads();  // staging visible

      bfv8 af[2][2];
#pragma unroll
      for (int fi = 0; fi < 2; ++fi) {
        const int row = wave * 32 + fi * 16 + m;
#pragma unroll
        for (int kh = 0; kh < 2; ++kh) {
          const int ch = (kh * 4 + kg) ^ (row & 7);
          af[fi][kh] = *(const bfv8*)(As + row * 64 + ch * 8);
        }
      }
#pragma unroll
      for (int fj = 0; fj < 4; ++fj) {
        const int row = fj * 16 + m;
        const bfv8 b0 = *(const bfv8*)(Bs + row * 64 + ((kg ^ (row & 7)) * 8));
        const bfv8 b1 =
            *(const bfv8*)(Bs + row * 64 + (((4 + kg) ^ (row & 7)) * 8));
#pragma unroll
        for (int fi = 0; fi < 2; ++fi) {
          acc[fi][fj] = __builtin_amdgcn_mfma_f32_16x16x32_bf16(
              af[fi][0], b0, acc[fi][fj], 0, 0, 0);
          acc[fi][fj] = __builtin_amdgcn_mfma_f32_16x16x32_bf16(
              af[fi][1], b1, acc[fi][fj], 0, 0, 0);
        }
      }
    }
    __syncthreads();  // frag reads done; Ct may overwrite staging

    // Transpose to Ct (C/D layout: col=lane&15, row=(lane>>4)*4+reg).
#pragma unroll
    for (int fi = 0; fi < 2; ++fi)
#pragma unroll
      for (int fj = 0; fj < 4; ++fj)
        *(fv4*)(&Ct[(fj * 16 + m) * 136 + wave * 32 + fi * 16 + kg * 4]) =
            acc[fi][fj];
    __syncthreads();

    // Selection: all 4 waves; thread = (row, col-half), 32 cols each.
    const int cbase = selhalf * 32;
#pragma unroll 1
    for (int cc = 0; cc < 32; ++cc) {
      const int c = cbase + cc;
      const float d =
          fmaxf(sqi_own - 2.f * Ct[c * 136 + selrow] + sqj_s[c], 0.f);
      const uint32 key = ((uint32)f2bf(d) << 16) | (uint32)(jbase + c);
      if (key < bk[NC - 1]) {
        uint32 kv = key;
#pragma unroll
        for (int t = 0; t < NC; ++t) {
          if (kv < bk[t]) {
            const uint32 tmp = bk[t];
            bk[t] = kv;
            kv = tmp;
          }
        }
      }
    }
  }

  const size_t obase =
      ((size_t)(ibase + selrow) * (GSPLIT * 2) + blockIdx.y * 2 + selhalf) * NC;
#pragma unroll
  for (int t = 0; t < NC; ++t) ck[obase + t] = bk[t];
}

// ---------------------------------------------------------------------------
// Kernel 2: per-row merge — WAVE-PER-ROW rewrite. One 64-lane wave owns one
// row end-to-end (4 rows/block): uint4 key load; 20-slot butterfly preselect;
// fp64 rescore (8 dims/lane, f64 butterfly, j via __shfl); validated serial
// eps-tie-break top-10 on lane 0 (per-wave LDS, 2 block barriers total);
// smoothing gather (winners L1/L2-warm from rescore).
// ---------------------------------------------------------------------------
__global__ __launch_bounds__(256) void merge_kernel(const float* __restrict__ x,
                                                    const float* __restrict__ sq,
                                                    const uint32* __restrict__ ck,
                                                    float* __restrict__ out) {
  __shared__ double zsh[4][TRS];
  __shared__ int jsh[4][TRS];
  __shared__ int jout[4][KNEI];

  const int wave = threadIdx.x >> 6;
  const int lane = threadIdx.x & 63;
  const int i = blockIdx.x * 4 + wave;

  // Own row: 8 dims per lane, kept in registers.
  const float4 xiA = *(const float4*)(x + (size_t)i * D + lane * 8);
  const float4 xiB = *(const float4*)(x + (size_t)i * D + lane * 8 + 4);
  const float sqi = sq[i];

  // Keys: 4 contiguous per lane (multiset identical to validated layout).
  const uint32* ckr = ck + (size_t)i * NTOT + lane * 4;
  uint32 l0 = ckr[0], l1 = ckr[1], l2 = ckr[2], l3 = ckr[3];

  // (1) top-20 by packed key (bf16 score, then lower index — keys unique).
  int myselj = 0;
#pragma unroll 1
  for (int slot = 0; slot < TRS; ++slot) {
    uint32 r = min(min(l0, l1), min(l2, l3));
#pragma unroll
    for (int off = 32; off; off >>= 1) r = min(r, __shfl_xor(r, off));
    if (lane == slot) myselj = (int)(r & 0xffffu);
    if (l0 == r) l0 = 0xffffffffu;
    if (l1 == r) l1 = 0xffffffffu;
    if (l2 == r) l2 = 0xffffffffu;
    if (l3 == r) l3 = 0xffffffffu;
  }

  // (2) fp64 rescore with the reference's fp32 rounding chain (validated).
  double myz = 0.0;
#pragma unroll 2
  for (int c = 0; c < TRS; ++c) {
    const int j = __shfl(myselj, c);
    const float4 a = *(const float4*)(x + (size_t)j * D + lane * 8);
    const float4 b = *(const float4*)(x + (size_t)j * D + lane * 8 + 4);
    double s = (double)xiA.x * a.x + (double)xiA.y * a.y +
               (double)xiA.z * a.z + (double)xiA.w * a.w +
               (double)xiB.x * b.x + (double)xiB.y * b.y +
               (double)xiB.z * b.z + (double)xiB.w * b.w;
#pragma unroll
    for (int off = 32; off; off >>= 1) s += __shfl_xor(s, off);
    if (lane == c) {
      const float G = (float)s;
      const float y = __fsub_rn(sqi, __fmul_rn(2.0f, G));
      myz = (double)y + (double)sq[j];
    }
  }
  if (lane < TRS) {
    zsh[wave][lane] = myz;
    jsh[wave][lane] = myselj;
  }
  __syncthreads();

  // (3) serial top-10, eps tie-break — comparator identical to rounds 3-7.
  if (lane == 0) {
    unsigned int used = 0u;
    for (int slot = 0; slot < KNEI; ++slot) {
      int b = -1;
      double zb = 0.0;
      for (int c = 0; c < TRS; ++c) {
        if ((used >> c) & 1u) continue;
        const double zc = zsh[wave][c];
        if (b < 0) {
          b = c;
          zb = zc;
          continue;
        }
        const double eps = 1.25e-7 * fabs(zb);
        bool better;
        if (zc < zb - eps) better = true;
        else if (zc > zb + eps) better = false;
        else better = (jsh[wave][c] < jsh[wave][b]);
        if (better) {
          b = c;
          zb = zc;
        }
      }
      used |= (1u << b);
      jout[wave][slot] = jsh[wave][b];
    }
  }
  __syncthreads();

  // (4) smoothed = 0.5*x + 0.05 * sum(neighbors); 8 dims per lane.
  float4 sA = {0.f, 0.f, 0.f, 0.f}, sB = {0.f, 0.f, 0.f, 0.f};
#pragma unroll
  for (int mth = 0; mth < KNEI; ++mth) {
    const int j = jout[wave][mth];
    const float4 a = *(const float4*)(x + (size_t)j * D + lane * 8);
    const float4 b = *(const float4*)(x + (size_t)j * D + lane * 8 + 4);
    sA.x += a.x; sA.y += a.y; sA.z += a.z; sA.w += a.w;
    sB.x += b.x; sB.y += b.y; sB.z += b.z; sB.w += b.w;
  }
  float4 oA, oB;
  oA.x = 0.5f * xiA.x + 0.05f * sA.x;
  oA.y = 0.5f * xiA.y + 0.05f * sA.y;
  oA.z = 0.5f * xiA.z + 0.05f * sA.z;
  oA.w = 0.5f * xiA.w + 0.05f * sA.w;
  oB.x = 0.5f * xiB.x + 0.05f * sB.x;
  oB.y = 0.5f * xiB.y + 0.05f * sB.y;
  oB.z = 0.5f * xiB.z + 0.05f * sB.z;
  oB.w = 0.5f * xiB.w + 0.05f * sB.w;
  *(float4*)(out + (size_t)i * D + lane * 8) = oA;
  *(float4*)(out + (size_t)i * D + lane * 8 + 4) = oB;
}

// ---------------------------------------------------------------------------
extern "C" void kernel_launch(void* const* d_in, const int* in_sizes, int n_in,
                              void* d_out, int out_size, void* d_ws, size_t ws_size,
                              hipStream_t stream) {
  const float* x = (const float*)d_in[0];
  float* out = (float*)d_out;

  char* ws = (char*)d_ws;
  float* sq = (float*)ws;                              // 32 KB
  unsigned short* xb = (unsigned short*)(ws + 32768);  // 8 MB
  uint32* ck = (uint32*)(ws + 32768 + 8388608);        // 8 MB

  row_sq_np_kernel<<<N / 4, 256, 0, stream>>>(x, sq);
  cvt_bf16_kernel<<<(N * D) / (8 * 256), 256, 0, stream>>>(x, xb);
  knn_gemm_mfma<<<dim3(N / 128, GSPLIT), 256, 0, stream>>>(xb, sq, ck);
  merge_kernel<<<N / 4, 256, 0, stream>>>(x, sq, ck, out);
}